// Round 10
// baseline (637.299 us; speedup 1.0000x reference)
//
#include <hip/hip_runtime.h>
#include <hip/hip_fp16.h>
#include <math.h>

#define GRID 896    // blocks of 256 thr; capacity @4 blocks/CU = 1024 > 896
#define NGSEL 56    // groups selected per row (56*16 = 896 candidates)
#define EXPK 14     // expansion slots/lane = NGSEL*16/64
#define NCELL 4096  // 16^3 Morton cells
#define MAGIC 0x13579BDFu

__device__ __forceinline__ uint32_t umin32(uint32_t a, uint32_t b) { return a < b ? a : b; }
__device__ __forceinline__ uint32_t umax32(uint32_t a, uint32_t b) { return a > b ? a : b; }

__device__ __forceinline__ uint32_t expand5(uint32_t x) {
  x &= 0x1Fu;
  x = (x | (x << 8)) & 0x100Fu;
  x = (x | (x << 4)) & 0x10C3u;
  x = (x | (x << 2)) & 0x1249u;
  return x;
}
__device__ __forceinline__ uint32_t cell_of(float gx, float gy, float gz) {
  int cx = (int)((gx + 3.2f) * 2.5f);
  int cy = (int)((gy + 3.2f) * 2.5f);
  int cz = (int)((gz + 3.2f) * 2.5f);
  cx = cx < 0 ? 0 : (cx > 15 ? 15 : cx);
  cy = cy < 0 ? 0 : (cy > 15 ? 15 : cy);
  cz = cz < 0 ? 0 : (cz > 15 ? 15 : cz);
  return expand5((uint32_t)cx) | (expand5((uint32_t)cy) << 1) | (expand5((uint32_t)cz) << 2);
}

// Software grid barrier: one-shot counter per phase boundary. All GRID blocks
// are co-resident (capacity 1024 @ launch_bounds(256,4)), so spinning is safe.
__device__ __forceinline__ void gbar(uint32_t* b) {
  __syncthreads();
  if (threadIdx.x == 0) {
    __threadfence();  // agent-scope release (L2 writeback on gfx950)
    __hip_atomic_fetch_add(b, 1u, __ATOMIC_RELEASE, __HIP_MEMORY_SCOPE_AGENT);
    while (__hip_atomic_load(b, __ATOMIC_ACQUIRE, __HIP_MEMORY_SCOPE_AGENT) < (uint32_t)GRID)
      __builtin_amdgcn_s_sleep(8);
  }
  __syncthreads();
}

__global__ __launch_bounds__(256, 4) void fused_kernel(
    const float* __restrict__ verts, const int* __restrict__ faces,
    const float* __restrict__ prob, float* __restrict__ out,
    uint32_t* __restrict__ bar,   // [0..4] barrier counters, [7] init flag
    uint32_t* __restrict__ hist, uint32_t* __restrict__ cursor,
    float4* __restrict__ scent, float4* __restrict__ snun,
    float4* __restrict__ sqa, float4* __restrict__ sqb, float4* __restrict__ sqc,
    ushort4* __restrict__ sfaces, float* __restrict__ sprob,
    float4* __restrict__ gcent, int F, int Fpad) {
  __shared__ uint32_t wsums[4];
  __shared__ unsigned short glist[4][64];
  __shared__ float blocksum;

  const int tid = threadIdx.x;
  const int gtid = blockIdx.x * 256 + tid;
  const int lane = tid & 63;
  const int wid = tid >> 6;

  // ---- init gate: block 0 zeroes counters + out, then raises MAGIC flag ----
  if (blockIdx.x == 0 && tid == 0) {
    for (int i = 0; i < 7; ++i)
      __hip_atomic_store(&bar[i], 0u, __ATOMIC_RELAXED, __HIP_MEMORY_SCOPE_AGENT);
    out[0] = 0.0f;
    __threadfence();
    __hip_atomic_store(&bar[7], MAGIC, __ATOMIC_RELEASE, __HIP_MEMORY_SCOPE_AGENT);
  }
  if (tid == 0) {
    while (__hip_atomic_load(&bar[7], __ATOMIC_ACQUIRE, __HIP_MEMORY_SCOPE_AGENT) != MAGIC)
      __builtin_amdgcn_s_sleep(8);
  }
  __syncthreads();

  // ---- phase 0: zero histogram ----
  if (gtid < NCELL) hist[gtid] = 0u;
  gbar(&bar[0]);

  // ---- phase 1: Morton-cell histogram ----
  if (gtid < F) {
    int i0 = faces[3*gtid+0], i1 = faces[3*gtid+1], i2 = faces[3*gtid+2];
    float gx = (verts[3*i0+0] + verts[3*i1+0] + verts[3*i2+0]) / 3.0f;
    float gy = (verts[3*i0+1] + verts[3*i1+1] + verts[3*i2+1]) / 3.0f;
    float gz = (verts[3*i0+2] + verts[3*i1+2] + verts[3*i2+2]) / 3.0f;
    atomicAdd(&hist[cell_of(gx, gy, gz)], 1u);
  }
  gbar(&bar[1]);

  // ---- phase 2: exclusive prefix sum over 4096 cells (block 0, 256 thr) ----
  if (blockIdx.x == 0) {
    uint32_t loc[16];
    uint32_t s = 0;
    const int base = tid * 16;   // 256 threads x 16 = 4096 cells
    #pragma unroll
    for (int i = 0; i < 16; ++i) { loc[i] = hist[base + i]; s += loc[i]; }
    uint32_t v = s;
    #pragma unroll
    for (int off = 1; off < 64; off <<= 1) {
      uint32_t u = (uint32_t)__shfl_up((int)v, off);
      if (lane >= off) v += u;
    }
    if (lane == 63) wsums[wid] = v;
    __syncthreads();
    if (wid == 0 && lane < 4) {
      uint32_t w = wsums[lane];
      #pragma unroll
      for (int off = 1; off < 4; off <<= 1) {
        uint32_t u = (uint32_t)__shfl_up((int)w, off);
        if (lane >= off) w += u;
      }
      wsums[lane] = w;
    }
    __syncthreads();
    uint32_t run = ((wid > 0) ? wsums[wid - 1] : 0u) + (v - s);
    #pragma unroll
    for (int i = 0; i < 16; ++i) { cursor[base + i] = run; run += loc[i]; }
  }
  gbar(&bar[2]);

  // ---- phase 3: recompute geometry, scatter into Morton-sorted order ----
  if (gtid < Fpad) {
    if (gtid >= F) {
      scent[gtid] = make_float4(300.f, 300.f, 300.f, 270000.f);
      float4 z = make_float4(0.f, 0.f, 0.f, 0.f);
      snun[gtid] = z; sqa[gtid] = z; sqb[gtid] = z; sqc[gtid] = z;
      sfaces[gtid] = make_ushort4(0xFFFFu, 0xFFFFu, 0xFFFFu, 0u);
      sprob[gtid] = 0.f;
    } else {
      int i0 = faces[3*gtid+0], i1 = faces[3*gtid+1], i2 = faces[3*gtid+2];
      float ax = verts[3*i0+0], ay = verts[3*i0+1], az = verts[3*i0+2];
      float bx = verts[3*i1+0], by = verts[3*i1+1], bz = verts[3*i1+2];
      float cx = verts[3*i2+0], cy = verts[3*i2+1], cz = verts[3*i2+2];
      float e1x = bx-ax, e1y = by-ay, e1z = bz-az;
      float e2x = cx-ax, e2y = cy-ay, e2z = cz-az;
      float nx = e1y*e2z - e1z*e2y;
      float ny = e1z*e2x - e1x*e2z;
      float nz = e1x*e2y - e1y*e2x;
      float gx = (ax+bx+cx)/3.0f, gy = (ay+by+cy)/3.0f, gz = (az+bz+cz)/3.0f;
      float sq = gx*gx + gy*gy + gz*gz;
      uint32_t pos = atomicAdd(&cursor[cell_of(gx, gy, gz)], 1u);
      scent[pos] = make_float4(gx, gy, gz, sq);
      snun[pos]  = make_float4(nx, ny, nz, 0.f);
      sqa[pos]   = make_float4(ax, ay, az, 0.f);
      sqb[pos]   = make_float4(bx, by, bz, 0.f);
      sqc[pos]   = make_float4(cx, cy, cz, 0.f);
      sfaces[pos] = make_ushort4((unsigned short)i0, (unsigned short)i1, (unsigned short)i2, 0u);
      sprob[pos] = prob[gtid];
    }
  }
  gbar(&bar[3]);

  // ---- phase 4: group (16 sorted faces) mean centers, f32 ----
  if (gtid < Fpad) {
    float4 c = scent[gtid];
    bool valid = c.x < 250.f;
    float x = valid ? c.x : 0.f, y = valid ? c.y : 0.f, z = valid ? c.z : 0.f;
    float n = valid ? 1.f : 0.f;
    #pragma unroll
    for (int m = 1; m < 16; m <<= 1) {
      x += __shfl_xor(x, m); y += __shfl_xor(y, m);
      z += __shfl_xor(z, m); n += __shfl_xor(n, m);
    }
    if ((tid & 15) == 0) {
      float4 o;
      if (n > 0.f) { float inv = 1.0f / n; o = make_float4(x*inv, y*inv, z*inv, 0.f); }
      else o = make_float4(300.f, 300.f, 300.f, 0.f);
      gcent[gtid >> 4] = o;
    }
  }
  gbar(&bar[4]);

  // ---- phase 5: persistent kNN + collision, one wave per row ----
  if (tid == 0) blocksum = 0.f;
  __syncthreads();

  const int giters = Fpad >> 10;               // ngroups/64 = 20
  const int nwaves = (GRID * 256) >> 6;
  const int gwave = gtid >> 6;
  const unsigned long long below = (lane == 0) ? 0ull : (~0ull >> (64 - lane));
  float wsum = 0.f;

  for (int row = gwave; row < F; row += nwaves) {
    const float4 ci = scent[row];
    const float sqi = ci.w;

    // -- scan group centers: key = (f16 d2 << 16) | groupid, top-4/lane --
    uint32_t b0 = ~0u, b1 = ~0u, b2 = ~0u, b3 = ~0u;
    for (int t = 0; t < giters; ++t) {
      float4 g = gcent[64*t + lane];
      float dx = g.x - ci.x, dy = g.y - ci.y, dz = g.z - ci.z;
      float d2 = fmaf(dz, dz, fmaf(dy, dy, dx*dx));
      uint32_t key = ((uint32_t)__half_as_ushort(__float2half_rn(d2)) << 16)
                     | (uint32_t)(64*t + lane);
      uint32_t c_ = key, t_;
      t_ = umin32(c_, b0); c_ = umax32(c_, b0); b0 = t_;
      t_ = umin32(c_, b1); c_ = umax32(c_, b1); b1 = t_;
      t_ = umin32(c_, b2); c_ = umax32(c_, b2); b2 = t_;
      b3 = umin32(c_, b3);
    }

    // -- threshold-1: NGSEL-th smallest group distance --
    uint32_t T = 0;
    #pragma unroll 1
    for (int bit = 14; bit >= 0; --bit) {
      uint32_t M = (T | (1u << bit)) << 16;
      int c = __popcll(__ballot(b0 < M)) + __popcll(__ballot(b1 < M)) +
              __popcll(__ballot(b2 < M)) + __popcll(__ballot(b3 < M));
      if (c < NGSEL) T |= (1u << bit);
    }
    const uint32_t lim = (T + 1) << 16;

    // -- compact selected group ids (prefill 0 so stale slots are safe) --
    glist[wid][lane] = 0;
    bool a0 = b0 < lim, a1 = b1 < lim, a2 = b2 < lim, a3 = b3 < lim;
    unsigned long long m0 = __ballot(a0), m1 = __ballot(a1);
    unsigned long long m2 = __ballot(a2), m3 = __ballot(a3);
    int n0 = __popcll(m0);
    int n01 = n0 + __popcll(m1);
    int n012 = n01 + __popcll(m2);
    int ngt = n012 + __popcll(m3);
    int ng = ngt < NGSEL ? ngt : NGSEL;
    int p0 = __popcll(m0 & below);
    int p1 = n0 + __popcll(m1 & below);
    int p2 = n01 + __popcll(m2 & below);
    int p3 = n012 + __popcll(m3 & below);
    if (a0 && p0 < 64) glist[wid][p0] = (unsigned short)(b0 & 0xFFFFu);
    if (a1 && p1 < 64) glist[wid][p1] = (unsigned short)(b1 & 0xFFFFu);
    if (a2 && p2 < 64) glist[wid][p2] = (unsigned short)(b2 & 0xFFFFu);
    if (a3 && p3 < 64) glist[wid][p3] = (unsigned short)(b3 & 0xFFFFu);

    // -- expansion, MLP-staged: all LDS reads, then all gathers --
    int gidx[EXPK];
    #pragma unroll
    for (int k = 0; k < EXPK; ++k)
      gidx[k] = 16 * (int)glist[wid][4*k + (lane >> 4)] + (lane & 15);
    float4 cj_[EXPK];
    #pragma unroll
    for (int k = 0; k < EXPK; ++k) cj_[k] = scent[gidx[k]];

    uint32_t e0 = ~0u, e1 = ~0u, e2 = ~0u, e3 = ~0u;
    #pragma unroll
    for (int k = 0; k < EXPK; ++k) {
      if (4*k + (lane >> 4) < ng) {
        float4 cj = cj_[k];
        float dot = fmaf(ci.x, cj.x, fmaf(ci.y, cj.y, ci.z * cj.z));
        float d2 = fmaxf(fmaf(-2.0f, dot, sqi + cj.w), 0.0f);
        uint32_t key = ((uint32_t)__half_as_ushort(__float2half_rn(d2)) << 16)
                       | (uint32_t)gidx[k];
        uint32_t c_ = key, t_;
        t_ = umin32(c_, e0); c_ = umax32(c_, e0); e0 = t_;
        t_ = umin32(c_, e1); c_ = umax32(c_, e1); e1 = t_;
        t_ = umin32(c_, e2); c_ = umax32(c_, e2); e2 = t_;
        e3 = umin32(c_, e3);
      }
    }

    // -- threshold-2: 51st smallest exact-f32 (f16-rounded) d2 --
    uint32_t T2 = 0;
    #pragma unroll 1
    for (int bit = 14; bit >= 0; --bit) {
      uint32_t M = (T2 | (1u << bit)) << 16;
      int c = __popcll(__ballot(e0 < M)) + __popcll(__ballot(e1 < M)) +
              __popcll(__ballot(e2 < M)) + __popcll(__ballot(e3 < M));
      if (c < 51) T2 |= (1u << bit);
    }
    const uint32_t lim2 = (T2 + 1) << 16;

    // -- compact neighbor ids (exclude self), reuse glist row --
    const uint32_t rw = (uint32_t)row;
    bool q0 = e0 < lim2 && (e0 & 0xFFFFu) != rw;
    bool q1 = e1 < lim2 && (e1 & 0xFFFFu) != rw;
    bool q2 = e2 < lim2 && (e2 & 0xFFFFu) != rw;
    bool q3 = e3 < lim2 && (e3 & 0xFFFFu) != rw;
    unsigned long long f0 = __ballot(q0), f1 = __ballot(q1);
    unsigned long long f2 = __ballot(q2), f3 = __ballot(q3);
    int c0 = __popcll(f0);
    int c01 = c0 + __popcll(f1);
    int c012 = c01 + __popcll(f2);
    int n = c012 + __popcll(f3);
    int s0 = __popcll(f0 & below);
    int s1 = c0 + __popcll(f1 & below);
    int s2 = c01 + __popcll(f2 & below);
    int s3 = c012 + __popcll(f3 & below);
    if (q0 && s0 < 64) glist[wid][s0] = (unsigned short)(e0 & 0xFFFFu);
    if (q1 && s1 < 64) glist[wid][s1] = (unsigned short)(e1 & 0xFFFFu);
    if (q2 && s2 < 64) glist[wid][s2] = (unsigned short)(e2 & 0xFFFFu);
    if (q3 && s3 < 64) glist[wid][s3] = (unsigned short)(e3 & 0xFFFFu);

    // -- predicate --
    const float4 nui = snun[row];
    const float inv_i = 1.0f / (sqrtf(nui.x*nui.x + nui.y*nui.y + nui.z*nui.z) + 1e-8f);
    const float4 ai  = sqa[row];
    const float4 bi  = sqb[row];
    const float4 civ = sqc[row];
    const ushort4 fi = sfaces[row];
    const int fi0 = fi.x, fi1 = fi.y, fi2 = fi.z;
    const bool first1 = (fi1 != fi0);
    const bool first2 = (fi2 != fi0) && (fi2 != fi1);

    bool coll = false;
    if (lane < (n < 64 ? n : 64)) {
      int j = (int)glist[wid][lane];
      float4 nuj = snun[j];
      float inv_j = 1.0f / (sqrtf(nuj.x*nuj.x + nuj.y*nuj.y + nuj.z*nuj.z) + 1e-8f);
      float ndot = fabsf(nui.x*nuj.x + nui.y*nuj.y + nui.z*nuj.z) * inv_i * inv_j;
      float4 cj = scent[j];
      float dx = ci.x - cj.x, dy = ci.y - cj.y, dz = ci.z - cj.z;
      bool cop_hit = sqrtf(dx*dx + dy*dy + dz*dz) < 1e-10f;
      float4 aj = sqa[j], bj = sqb[j], cjv = sqc[j];
      float dA0 = (aj.x-ai.x)*nui.x + (aj.y-ai.y)*nui.y + (aj.z-ai.z)*nui.z;
      float dA1 = (bj.x-ai.x)*nui.x + (bj.y-ai.y)*nui.y + (bj.z-ai.z)*nui.z;
      float dA2 = (cjv.x-ai.x)*nui.x + (cjv.y-ai.y)*nui.y + (cjv.z-ai.z)*nui.z;
      bool condA = (dA0*dA1 <= 0.f) || (dA0*dA2 <= 0.f) || (dA1*dA2 <= 0.f);
      float dB0 = (ai.x-aj.x)*nuj.x + (ai.y-aj.y)*nuj.y + (ai.z-aj.z)*nuj.z;
      float dB1 = (bi.x-aj.x)*nuj.x + (bi.y-aj.y)*nuj.y + (bi.z-aj.z)*nuj.z;
      float dB2 = (civ.x-aj.x)*nuj.x + (civ.y-aj.y)*nuj.y + (civ.z-aj.z)*nuj.z;
      bool condB = (dB0*dB1 <= 0.f) || (dB0*dB2 <= 0.f) || (dB1*dB2 <= 0.f);
      bool inter = (ndot > 0.99f) ? cop_hit : (condA && condB);
      ushort4 gj = sfaces[j];
      int g0 = gj.x, g1 = gj.y, g2 = gj.z;
      int shared_ = 0;
      shared_ += ((fi0==g0) | (fi0==g1) | (fi0==g2)) ? 1 : 0;
      shared_ += (first1 && ((fi1==g0) | (fi1==g1) | (fi1==g2))) ? 1 : 0;
      shared_ += (first2 && ((fi2==g0) | (fi2==g1) | (fi2==g2))) ? 1 : 0;
      coll = inter && (shared_ < 2);
    }
    unsigned long long cm = __ballot(coll);
    if (lane == 0) wsum += sprob[row] * (float)__popcll(cm);
  }

  if (lane == 0) atomicAdd(&blocksum, wsum);
  __syncthreads();
  if (tid == 0 && blocksum != 0.f) atomicAdd(out, blocksum);
}

extern "C" void kernel_launch(void* const* d_in, const int* in_sizes, int n_in,
                              void* d_out, int out_size, void* d_ws, size_t ws_size,
                              hipStream_t stream) {
  const float* verts = (const float*)d_in[0];
  const int*   faces = (const int*)d_in[1];
  const float* prob  = (const float*)d_in[2];
  float* out = (float*)d_out;
  int F = in_sizes[1] / 3;
  int Fpad = (F + 2047) & ~2047;   // 20480: 1280 groups of 16
  const int ngroups = Fpad / 16;

  char* ws = (char*)d_ws;
  uint32_t* bar    = (uint32_t*)ws;                       ws += 32;
  uint32_t* hist   = (uint32_t*)ws;                       ws += NCELL * 4;
  uint32_t* cursor = (uint32_t*)ws;                       ws += NCELL * 4;
  float4* scent = (float4*)ws;                            ws += (size_t)Fpad * 16;
  float4* snun  = (float4*)ws;                            ws += (size_t)Fpad * 16;
  float4* sqa   = (float4*)ws;                            ws += (size_t)Fpad * 16;
  float4* sqb   = (float4*)ws;                            ws += (size_t)Fpad * 16;
  float4* sqc   = (float4*)ws;                            ws += (size_t)Fpad * 16;
  ushort4* sfaces = (ushort4*)ws;                         ws += (size_t)Fpad * 8;
  float* sprob  = (float*)ws;                             ws += (size_t)Fpad * 4;
  float4* gcent = (float4*)ws;                            ws += (size_t)ngroups * 16;

  fused_kernel<<<GRID, 256, 0, stream>>>(
      verts, faces, prob, out, bar, hist, cursor,
      scent, snun, sqa, sqb, sqc, sfaces, sprob, gcent, F, Fpad);
}

// Round 11
// 312.193 us; speedup vs baseline: 2.0414x; 2.0414x over previous
//
#include <hip/hip_runtime.h>
#include <hip/hip_fp16.h>
#include <math.h>

#define WPB 4       // waves per block (knn); 1 row per wave
#define NGSEL 56    // groups selected per row (56*16 = 896 candidates)
#define EXPK 14     // expansion slots/lane = NGSEL*16/64
#define NCELL 4096  // 16^3 Morton cells

__device__ __forceinline__ uint32_t umin32(uint32_t a, uint32_t b) { return a < b ? a : b; }
__device__ __forceinline__ uint32_t umax32(uint32_t a, uint32_t b) { return a > b ? a : b; }

__device__ __forceinline__ uint32_t expand5(uint32_t x) {
  x &= 0x1Fu;
  x = (x | (x << 8)) & 0x100Fu;
  x = (x | (x << 4)) & 0x10C3u;
  x = (x | (x << 2)) & 0x1249u;
  return x;
}
__device__ __forceinline__ uint32_t cell_of(float gx, float gy, float gz) {
  int cx = (int)((gx + 3.2f) * 2.5f);
  int cy = (int)((gy + 3.2f) * 2.5f);
  int cz = (int)((gz + 3.2f) * 2.5f);
  cx = cx < 0 ? 0 : (cx > 15 ? 15 : cx);
  cy = cy < 0 ? 0 : (cy > 15 ? 15 : cy);
  cz = cz < 0 ? 0 : (cz > 15 ? 15 : cz);
  return expand5((uint32_t)cx) | (expand5((uint32_t)cy) << 1) | (expand5((uint32_t)cz) << 2);
}

// ---- Prep: ONE 1024-thread workgroup does hist -> scan -> scatter ->
// group means, using __syncthreads (ns) instead of grid barriers (~85 us
// each, measured R10) or separate launches (~16 us each, measured R8).
// Single block on one CU: global writes/reads between phases go through the
// same L1; the compiler's vmcnt-before-barrier drain makes them visible.
__global__ __launch_bounds__(1024) void prep_kernel(
    const float* __restrict__ verts, const int* __restrict__ faces,
    const float* __restrict__ prob, float* __restrict__ out,
    float4* __restrict__ scent, float4* __restrict__ snun,
    float4* __restrict__ sqa, float4* __restrict__ sqb, float4* __restrict__ sqc,
    ushort4* __restrict__ sfaces, float* __restrict__ sprob,
    float4* __restrict__ gcent, int F, int Fpad) {
  __shared__ uint32_t hist[NCELL];     // histogram, then exclusive cursor
  __shared__ uint32_t wsums[16];
  const int tid = threadIdx.x;
  const int lane = tid & 63, wid = tid >> 6;

  if (tid == 0) out[0] = 0.0f;
  for (int i = tid; i < NCELL; i += 1024) hist[i] = 0u;
  __syncthreads();

  // -- phase A: Morton-cell histogram --
  for (int f = tid; f < F; f += 1024) {
    int i0 = faces[3*f+0], i1 = faces[3*f+1], i2 = faces[3*f+2];
    float gx = (verts[3*i0+0] + verts[3*i1+0] + verts[3*i2+0]) / 3.0f;
    float gy = (verts[3*i0+1] + verts[3*i1+1] + verts[3*i2+1]) / 3.0f;
    float gz = (verts[3*i0+2] + verts[3*i1+2] + verts[3*i2+2]) / 3.0f;
    atomicAdd(&hist[cell_of(gx, gy, gz)], 1u);
  }
  __syncthreads();

  // -- phase B: exclusive prefix sum (1024 thr x 4 cells) --
  uint32_t loc[4];
  uint32_t s = 0;
  const int base = tid * 4;
  #pragma unroll
  for (int i = 0; i < 4; ++i) { loc[i] = hist[base + i]; s += loc[i]; }
  uint32_t v = s;
  #pragma unroll
  for (int off = 1; off < 64; off <<= 1) {
    uint32_t u = (uint32_t)__shfl_up((int)v, off);
    if (lane >= off) v += u;
  }
  if (lane == 63) wsums[wid] = v;
  __syncthreads();
  if (wid == 0 && lane < 16) {
    uint32_t w = wsums[lane];
    #pragma unroll
    for (int off = 1; off < 16; off <<= 1) {
      uint32_t u = (uint32_t)__shfl_up((int)w, off);
      if (lane >= off) w += u;
    }
    wsums[lane] = w;
  }
  __syncthreads();   // also guarantees all phase-B reads of hist[] are done
  uint32_t run = ((wid > 0) ? wsums[wid - 1] : 0u) + (v - s);
  #pragma unroll
  for (int i = 0; i < 4; ++i) { hist[base + i] = run; run += loc[i]; }
  __syncthreads();

  // -- phase C: recompute geometry, scatter into Morton-sorted order --
  for (int f = tid; f < Fpad; f += 1024) {
    if (f >= F) {      // pads land exactly in slots [F, Fpad)
      scent[f] = make_float4(300.f, 300.f, 300.f, 270000.f);
      float4 z = make_float4(0.f, 0.f, 0.f, 0.f);
      snun[f] = z; sqa[f] = z; sqb[f] = z; sqc[f] = z;
      sfaces[f] = make_ushort4(0xFFFFu, 0xFFFFu, 0xFFFFu, 0u);
      sprob[f] = 0.f;
    } else {
      int i0 = faces[3*f+0], i1 = faces[3*f+1], i2 = faces[3*f+2];
      float ax = verts[3*i0+0], ay = verts[3*i0+1], az = verts[3*i0+2];
      float bx = verts[3*i1+0], by = verts[3*i1+1], bz = verts[3*i1+2];
      float cx = verts[3*i2+0], cy = verts[3*i2+1], cz = verts[3*i2+2];
      float e1x = bx-ax, e1y = by-ay, e1z = bz-az;
      float e2x = cx-ax, e2y = cy-ay, e2z = cz-az;
      float nx = e1y*e2z - e1z*e2y;
      float ny = e1z*e2x - e1x*e2z;
      float nz = e1x*e2y - e1y*e2x;
      float gx = (ax+bx+cx)/3.0f, gy = (ay+by+cy)/3.0f, gz = (az+bz+cz)/3.0f;
      float sq = gx*gx + gy*gy + gz*gz;
      uint32_t pos = atomicAdd(&hist[cell_of(gx, gy, gz)], 1u);
      scent[pos] = make_float4(gx, gy, gz, sq);
      snun[pos]  = make_float4(nx, ny, nz, 0.f);
      sqa[pos]   = make_float4(ax, ay, az, 0.f);
      sqb[pos]   = make_float4(bx, by, bz, 0.f);
      sqc[pos]   = make_float4(cx, cy, cz, 0.f);
      sfaces[pos] = make_ushort4((unsigned short)i0, (unsigned short)i1, (unsigned short)i2, 0u);
      sprob[pos] = prob[f];
    }
  }
  __syncthreads();

  // -- phase D: group (16 sorted faces) mean centers, f32 --
  for (int b = tid; b < Fpad; b += 1024) {
    float4 c = scent[b];
    bool valid = c.x < 250.f;
    float x = valid ? c.x : 0.f, y = valid ? c.y : 0.f, z = valid ? c.z : 0.f;
    float n = valid ? 1.f : 0.f;
    #pragma unroll
    for (int m = 1; m < 16; m <<= 1) {
      x += __shfl_xor(x, m); y += __shfl_xor(y, m);
      z += __shfl_xor(z, m); n += __shfl_xor(n, m);
    }
    if ((tid & 15) == 0) {
      float4 o;
      if (n > 0.f) { float inv = 1.0f / n; o = make_float4(x*inv, y*inv, z*inv, 0.f); }
      else o = make_float4(300.f, 300.f, 300.f, 0.f);
      gcent[b >> 4] = o;
    }
  }
}

// ---- knn+collision: one wave per row (R8/R10-proven logic) ----
__global__ __launch_bounds__(WPB * 64) void knn_collide_kernel(
    const float4* __restrict__ gcent,
    const float4* __restrict__ scent, const float4* __restrict__ snun,
    const float4* __restrict__ sqa, const float4* __restrict__ sqb,
    const float4* __restrict__ sqc, const ushort4* __restrict__ sfaces,
    const float* __restrict__ sprob,
    float* __restrict__ out, int F, int giters) {
  __shared__ float blocksum;
  __shared__ unsigned short glist[WPB][64];
  const int tid = threadIdx.x;
  const int lane = tid & 63;
  const int wid = tid >> 6;
  const int row = blockIdx.x * WPB + wid;
  if (tid == 0) blocksum = 0.f;
  __syncthreads();
  const unsigned long long below = (lane == 0) ? 0ull : (~0ull >> (64 - lane));

  if (row < F) {
    const float4 ci = scent[row];
    const float sqi = ci.w;

    // -- scan group centers: key = (f16 d2 << 16) | groupid, top-4/lane --
    uint32_t b0 = ~0u, b1 = ~0u, b2 = ~0u, b3 = ~0u;
    for (int t = 0; t < giters; ++t) {
      float4 g = gcent[64*t + lane];
      float dx = g.x - ci.x, dy = g.y - ci.y, dz = g.z - ci.z;
      float d2 = fmaf(dz, dz, fmaf(dy, dy, dx*dx));
      uint32_t key = ((uint32_t)__half_as_ushort(__float2half_rn(d2)) << 16)
                     | (uint32_t)(64*t + lane);
      uint32_t c_ = key, t_;
      t_ = umin32(c_, b0); c_ = umax32(c_, b0); b0 = t_;
      t_ = umin32(c_, b1); c_ = umax32(c_, b1); b1 = t_;
      t_ = umin32(c_, b2); c_ = umax32(c_, b2); b2 = t_;
      b3 = umin32(c_, b3);
    }

    // -- threshold-1: NGSEL-th smallest group distance --
    uint32_t T = 0;
    #pragma unroll 1
    for (int bit = 14; bit >= 0; --bit) {
      uint32_t M = (T | (1u << bit)) << 16;
      int c = __popcll(__ballot(b0 < M)) + __popcll(__ballot(b1 < M)) +
              __popcll(__ballot(b2 < M)) + __popcll(__ballot(b3 < M));
      if (c < NGSEL) T |= (1u << bit);
    }
    const uint32_t lim = (T + 1) << 16;

    // -- compact selected group ids (prefill 0: stale slots are safe) --
    glist[wid][lane] = 0;
    bool a0 = b0 < lim, a1 = b1 < lim, a2 = b2 < lim, a3 = b3 < lim;
    unsigned long long m0 = __ballot(a0), m1 = __ballot(a1);
    unsigned long long m2 = __ballot(a2), m3 = __ballot(a3);
    int n0 = __popcll(m0);
    int n01 = n0 + __popcll(m1);
    int n012 = n01 + __popcll(m2);
    int ngt = n012 + __popcll(m3);
    int ng = ngt < NGSEL ? ngt : NGSEL;
    int p0 = __popcll(m0 & below);
    int p1 = n0 + __popcll(m1 & below);
    int p2 = n01 + __popcll(m2 & below);
    int p3 = n012 + __popcll(m3 & below);
    if (a0 && p0 < 64) glist[wid][p0] = (unsigned short)(b0 & 0xFFFFu);
    if (a1 && p1 < 64) glist[wid][p1] = (unsigned short)(b1 & 0xFFFFu);
    if (a2 && p2 < 64) glist[wid][p2] = (unsigned short)(b2 & 0xFFFFu);
    if (a3 && p3 < 64) glist[wid][p3] = (unsigned short)(b3 & 0xFFFFu);

    // -- expansion, MLP-staged: all LDS reads, then all gathers --
    int gidx[EXPK];
    #pragma unroll
    for (int k = 0; k < EXPK; ++k)
      gidx[k] = 16 * (int)glist[wid][4*k + (lane >> 4)] + (lane & 15);
    float4 cj_[EXPK];
    #pragma unroll
    for (int k = 0; k < EXPK; ++k) cj_[k] = scent[gidx[k]];

    uint32_t e0 = ~0u, e1 = ~0u, e2 = ~0u, e3 = ~0u;
    #pragma unroll
    for (int k = 0; k < EXPK; ++k) {
      if (4*k + (lane >> 4) < ng) {
        float4 cj = cj_[k];
        float dot = fmaf(ci.x, cj.x, fmaf(ci.y, cj.y, ci.z * cj.z));
        float d2 = fmaxf(fmaf(-2.0f, dot, sqi + cj.w), 0.0f);
        uint32_t key = ((uint32_t)__half_as_ushort(__float2half_rn(d2)) << 16)
                       | (uint32_t)gidx[k];
        uint32_t c_ = key, t_;
        t_ = umin32(c_, e0); c_ = umax32(c_, e0); e0 = t_;
        t_ = umin32(c_, e1); c_ = umax32(c_, e1); e1 = t_;
        t_ = umin32(c_, e2); c_ = umax32(c_, e2); e2 = t_;
        e3 = umin32(c_, e3);
      }
    }

    // -- threshold-2: 51st smallest exact-f32 (f16-rounded) d2 --
    uint32_t T2 = 0;
    #pragma unroll 1
    for (int bit = 14; bit >= 0; --bit) {
      uint32_t M = (T2 | (1u << bit)) << 16;
      int c = __popcll(__ballot(e0 < M)) + __popcll(__ballot(e1 < M)) +
              __popcll(__ballot(e2 < M)) + __popcll(__ballot(e3 < M));
      if (c < 51) T2 |= (1u << bit);
    }
    const uint32_t lim2 = (T2 + 1) << 16;

    // -- compact neighbor ids (exclude self), reuse glist row --
    const uint32_t rw = (uint32_t)row;
    bool q0 = e0 < lim2 && (e0 & 0xFFFFu) != rw;
    bool q1 = e1 < lim2 && (e1 & 0xFFFFu) != rw;
    bool q2 = e2 < lim2 && (e2 & 0xFFFFu) != rw;
    bool q3 = e3 < lim2 && (e3 & 0xFFFFu) != rw;
    unsigned long long f0 = __ballot(q0), f1 = __ballot(q1);
    unsigned long long f2 = __ballot(q2), f3 = __ballot(q3);
    int c0 = __popcll(f0);
    int c01 = c0 + __popcll(f1);
    int c012 = c01 + __popcll(f2);
    int n = c012 + __popcll(f3);
    int s0 = __popcll(f0 & below);
    int s1 = c0 + __popcll(f1 & below);
    int s2 = c01 + __popcll(f2 & below);
    int s3 = c012 + __popcll(f3 & below);
    if (q0 && s0 < 64) glist[wid][s0] = (unsigned short)(e0 & 0xFFFFu);
    if (q1 && s1 < 64) glist[wid][s1] = (unsigned short)(e1 & 0xFFFFu);
    if (q2 && s2 < 64) glist[wid][s2] = (unsigned short)(e2 & 0xFFFFu);
    if (q3 && s3 < 64) glist[wid][s3] = (unsigned short)(e3 & 0xFFFFu);

    // -- predicate --
    const float4 nui = snun[row];
    const float inv_i = 1.0f / (sqrtf(nui.x*nui.x + nui.y*nui.y + nui.z*nui.z) + 1e-8f);
    const float4 ai  = sqa[row];
    const float4 bi  = sqb[row];
    const float4 civ = sqc[row];
    const ushort4 fi = sfaces[row];
    const int fi0 = fi.x, fi1 = fi.y, fi2 = fi.z;
    const bool first1 = (fi1 != fi0);
    const bool first2 = (fi2 != fi0) && (fi2 != fi1);

    bool coll = false;
    if (lane < (n < 64 ? n : 64)) {
      int j = (int)glist[wid][lane];
      float4 nuj = snun[j];
      float inv_j = 1.0f / (sqrtf(nuj.x*nuj.x + nuj.y*nuj.y + nuj.z*nuj.z) + 1e-8f);
      float ndot = fabsf(nui.x*nuj.x + nui.y*nuj.y + nui.z*nuj.z) * inv_i * inv_j;
      float4 cj = scent[j];
      float dx = ci.x - cj.x, dy = ci.y - cj.y, dz = ci.z - cj.z;
      bool cop_hit = sqrtf(dx*dx + dy*dy + dz*dz) < 1e-10f;
      float4 aj = sqa[j], bj = sqb[j], cjv = sqc[j];
      float dA0 = (aj.x-ai.x)*nui.x + (aj.y-ai.y)*nui.y + (aj.z-ai.z)*nui.z;
      float dA1 = (bj.x-ai.x)*nui.x + (bj.y-ai.y)*nui.y + (bj.z-ai.z)*nui.z;
      float dA2 = (cjv.x-ai.x)*nui.x + (cjv.y-ai.y)*nui.y + (cjv.z-ai.z)*nui.z;
      bool condA = (dA0*dA1 <= 0.f) || (dA0*dA2 <= 0.f) || (dA1*dA2 <= 0.f);
      float dB0 = (ai.x-aj.x)*nuj.x + (ai.y-aj.y)*nuj.y + (ai.z-aj.z)*nuj.z;
      float dB1 = (bi.x-aj.x)*nuj.x + (bi.y-aj.y)*nuj.y + (bi.z-aj.z)*nuj.z;
      float dB2 = (civ.x-aj.x)*nuj.x + (civ.y-aj.y)*nuj.y + (civ.z-aj.z)*nuj.z;
      bool condB = (dB0*dB1 <= 0.f) || (dB0*dB2 <= 0.f) || (dB1*dB2 <= 0.f);
      bool inter = (ndot > 0.99f) ? cop_hit : (condA && condB);
      ushort4 gj = sfaces[j];
      int g0 = gj.x, g1 = gj.y, g2 = gj.z;
      int shared_ = 0;
      shared_ += ((fi0==g0) | (fi0==g1) | (fi0==g2)) ? 1 : 0;
      shared_ += (first1 && ((fi1==g0) | (fi1==g1) | (fi1==g2))) ? 1 : 0;
      shared_ += (first2 && ((fi2==g0) | (fi2==g1) | (fi2==g2))) ? 1 : 0;
      coll = inter && (shared_ < 2);
    }
    unsigned long long cm = __ballot(coll);
    if (lane == 0) atomicAdd(&blocksum, sprob[row] * (float)__popcll(cm));
  }

  __syncthreads();
  if (tid == 0 && blocksum != 0.f) atomicAdd(out, blocksum);
}

extern "C" void kernel_launch(void* const* d_in, const int* in_sizes, int n_in,
                              void* d_out, int out_size, void* d_ws, size_t ws_size,
                              hipStream_t stream) {
  const float* verts = (const float*)d_in[0];
  const int*   faces = (const int*)d_in[1];
  const float* prob  = (const float*)d_in[2];
  float* out = (float*)d_out;
  int F = in_sizes[1] / 3;
  int Fpad = (F + 2047) & ~2047;   // 20480: 1280 groups of 16
  const int ngroups = Fpad / 16;
  const int giters = ngroups / 64; // 20

  char* ws = (char*)d_ws;
  float4* scent = (float4*)ws;                            ws += (size_t)Fpad * 16;
  float4* snun  = (float4*)ws;                            ws += (size_t)Fpad * 16;
  float4* sqa   = (float4*)ws;                            ws += (size_t)Fpad * 16;
  float4* sqb   = (float4*)ws;                            ws += (size_t)Fpad * 16;
  float4* sqc   = (float4*)ws;                            ws += (size_t)Fpad * 16;
  ushort4* sfaces = (ushort4*)ws;                         ws += (size_t)Fpad * 8;
  float* sprob  = (float*)ws;                             ws += (size_t)Fpad * 4;
  float4* gcent = (float4*)ws;                            ws += (size_t)ngroups * 16;

  prep_kernel<<<1, 1024, 0, stream>>>(
      verts, faces, prob, out, scent, snun, sqa, sqb, sqc, sfaces, sprob,
      gcent, F, Fpad);

  int blocks = (F + WPB - 1) / WPB;
  knn_collide_kernel<<<blocks, WPB * 64, 0, stream>>>(
      gcent, scent, snun, sqa, sqb, sqc, sfaces, sprob, out, F, giters);
}

// Round 12
// 168.131 us; speedup vs baseline: 3.7905x; 1.8568x over previous
//
#include <hip/hip_runtime.h>
#include <hip/hip_fp16.h>
#include <math.h>

#define WPB 4       // waves per block (knn); 1 row per wave
#define EXPK 16     // expansion slots/lane = 64 groups * 16 / 64 lanes
#define NCELL 4096  // 16^3 Morton cells

__device__ __forceinline__ uint32_t umin32(uint32_t a, uint32_t b) { return a < b ? a : b; }
__device__ __forceinline__ uint32_t umax32(uint32_t a, uint32_t b) { return a > b ? a : b; }

__device__ __forceinline__ uint32_t expand5(uint32_t x) {
  x &= 0x1Fu;
  x = (x | (x << 8)) & 0x100Fu;
  x = (x | (x << 4)) & 0x10C3u;
  x = (x | (x << 2)) & 0x1249u;
  return x;
}
__device__ __forceinline__ uint32_t cell_of(float gx, float gy, float gz) {
  int cx = (int)((gx + 3.2f) * 2.5f);
  int cy = (int)((gy + 3.2f) * 2.5f);
  int cz = (int)((gz + 3.2f) * 2.5f);
  cx = cx < 0 ? 0 : (cx > 15 ? 15 : cx);
  cy = cy < 0 ? 0 : (cy > 15 ? 15 : cy);
  cz = cz < 0 ? 0 : (cz > 15 ? 15 : cz);
  return expand5((uint32_t)cx) | (expand5((uint32_t)cy) << 1) | (expand5((uint32_t)cz) << 2);
}

// ---- sortprep: ONE multi-block kernel does hist -> scan -> scatter ----
// Producer/consumer, not a grid barrier: all blocks hist-atomicAdd + arrive;
// block 0 (after seeing gridDim arrivals) scans 4096 cells and raises a
// flag; all blocks poll the single flag then scatter. 80 blocks <= 256 CUs
// -> all co-resident by construction, so spinning cannot deadlock.
// bar/hist/gcentsum are pre-zeroed by a hipMemsetAsync node.
__global__ __launch_bounds__(256) void sortprep_kernel(
    const float* __restrict__ verts, const int* __restrict__ faces,
    const float* __restrict__ prob, float* __restrict__ out,
    uint32_t* __restrict__ bar, uint32_t* __restrict__ hist,
    uint32_t* __restrict__ cursor,
    float4* __restrict__ scent, float4* __restrict__ snun,
    float4* __restrict__ sqa, float4* __restrict__ sqb, float4* __restrict__ sqc,
    ushort4* __restrict__ sfaces, float* __restrict__ sprob,
    float4* __restrict__ gcentsum, int F) {
  __shared__ uint32_t wsums[4];
  const int tid = threadIdx.x;
  const int lane = tid & 63, wid = tid >> 6;
  const int f = blockIdx.x * 256 + tid;
  if (f == 0) out[0] = 0.0f;

  // -- phase A: centroid + cell + histogram (geometry kept in registers) --
  bool valid = (f < F);
  int i0 = 0, i1 = 0, i2 = 0;
  float ax=0,ay=0,az=0,bx=0,by=0,bz=0,cx=0,cy=0,cz=0;
  float gx=0,gy=0,gz=0,sq=0;
  uint32_t cell = 0;
  if (valid) {
    i0 = faces[3*f+0]; i1 = faces[3*f+1]; i2 = faces[3*f+2];
    ax = verts[3*i0+0]; ay = verts[3*i0+1]; az = verts[3*i0+2];
    bx = verts[3*i1+0]; by = verts[3*i1+1]; bz = verts[3*i1+2];
    cx = verts[3*i2+0]; cy = verts[3*i2+1]; cz = verts[3*i2+2];
    gx = (ax+bx+cx)/3.0f; gy = (ay+by+cy)/3.0f; gz = (az+bz+cz)/3.0f;
    sq = gx*gx + gy*gy + gz*gz;
    cell = cell_of(gx, gy, gz);
    atomicAdd(&hist[cell], 1u);
  }
  __syncthreads();
  if (tid == 0) {
    __threadfence();
    __hip_atomic_fetch_add(&bar[0], 1u, __ATOMIC_RELEASE, __HIP_MEMORY_SCOPE_AGENT);
  }

  // -- block 0: wait all arrivals, exclusive-scan hist -> cursor, raise flag --
  if (blockIdx.x == 0) {
    if (tid == 0) {
      while (__hip_atomic_load(&bar[0], __ATOMIC_ACQUIRE, __HIP_MEMORY_SCOPE_AGENT)
             < gridDim.x)
        __builtin_amdgcn_s_sleep(2);
      __threadfence();
    }
    __syncthreads();
    uint32_t loc[16];
    uint32_t s = 0;
    const int base = tid * 16;   // 256 thr x 16 = 4096 cells
    #pragma unroll
    for (int i = 0; i < 16; ++i) { loc[i] = hist[base + i]; s += loc[i]; }
    uint32_t v = s;
    #pragma unroll
    for (int off = 1; off < 64; off <<= 1) {
      uint32_t u = (uint32_t)__shfl_up((int)v, off);
      if (lane >= off) v += u;
    }
    if (lane == 63) wsums[wid] = v;
    __syncthreads();
    if (wid == 0 && lane < 4) {
      uint32_t w = wsums[lane];
      #pragma unroll
      for (int off = 1; off < 4; off <<= 1) {
        uint32_t u = (uint32_t)__shfl_up((int)w, off);
        if (lane >= off) w += u;
      }
      wsums[lane] = w;
    }
    __syncthreads();
    uint32_t run = ((wid > 0) ? wsums[wid - 1] : 0u) + (v - s);
    #pragma unroll
    for (int i = 0; i < 16; ++i) { cursor[base + i] = run; run += loc[i]; }
    __syncthreads();
    if (tid == 0) {
      __threadfence();
      __hip_atomic_store(&bar[1], 1u, __ATOMIC_RELEASE, __HIP_MEMORY_SCOPE_AGENT);
    }
  }

  // -- all blocks: poll the flag --
  if (tid == 0) {
    while (__hip_atomic_load(&bar[1], __ATOMIC_ACQUIRE, __HIP_MEMORY_SCOPE_AGENT) == 0u)
      __builtin_amdgcn_s_sleep(2);
  }
  __syncthreads();

  // -- phase C: scatter into Morton-sorted order + group-sum atomics --
  if (valid) {
    float e1x = bx-ax, e1y = by-ay, e1z = bz-az;
    float e2x = cx-ax, e2y = cy-ay, e2z = cz-az;
    float nx = e1y*e2z - e1z*e2y;
    float ny = e1z*e2x - e1x*e2z;
    float nz = e1x*e2y - e1y*e2x;
    uint32_t pos = atomicAdd(&cursor[cell], 1u);
    scent[pos] = make_float4(gx, gy, gz, sq);
    snun[pos]  = make_float4(nx, ny, nz, 0.f);
    sqa[pos]   = make_float4(ax, ay, az, 0.f);
    sqb[pos]   = make_float4(bx, by, bz, 0.f);
    sqc[pos]   = make_float4(cx, cy, cz, 0.f);
    sfaces[pos] = make_ushort4((unsigned short)i0, (unsigned short)i1, (unsigned short)i2, 0u);
    sprob[pos] = prob[f];
    float* gs = (float*)&gcentsum[pos >> 4];
    atomicAdd(gs + 0, gx);
    atomicAdd(gs + 1, gy);
    atomicAdd(gs + 2, gz);
    atomicAdd(gs + 3, 1.0f);
  }
}

// ---- knn+collision: one wave per row. Per-lane TOP-1 group over the
// lane's 20-group stripe (Morton-sorted -> nearest groups have consecutive
// ids -> land in distinct lanes). 64 groups -> 1024 candidates, exact f32
// re-rank (f16-rounded keys, R7-validated), 51st-threshold, predicate.
__global__ __launch_bounds__(WPB * 64) void knn_collide_kernel(
    const float4* __restrict__ gcentsum,
    const float4* __restrict__ scent, const float4* __restrict__ snun,
    const float4* __restrict__ sqa, const float4* __restrict__ sqb,
    const float4* __restrict__ sqc, const ushort4* __restrict__ sfaces,
    const float* __restrict__ sprob,
    float* __restrict__ out, int F, int giters) {
  __shared__ float blocksum;
  __shared__ unsigned short glist[WPB][64];
  const int tid = threadIdx.x;
  const int lane = tid & 63;
  const int wid = tid >> 6;
  const int row = blockIdx.x * WPB + wid;
  if (tid == 0) blocksum = 0.f;
  __syncthreads();
  const unsigned long long below = (lane == 0) ? 0ull : (~0ull >> (64 - lane));

  if (row < F) {
    const float4 ci = scent[row];
    const float sqi = ci.w;

    // -- scan: per-lane top-1 group (key = f16 d2 << 16 | gid) --
    uint32_t best = ~0u;
    for (int t = 0; t < giters; ++t) {
      float4 g = gcentsum[64*t + lane];
      float mx = g.x * 0.0625f - ci.x;   // groups are full (16) when real
      float my = g.y * 0.0625f - ci.y;
      float mz = g.z * 0.0625f - ci.z;
      float d2 = fmaf(mz, mz, fmaf(my, my, mx*mx));
      uint32_t key = ((uint32_t)__half_as_ushort(__float2half_rn(d2)) << 16)
                     | (uint32_t)(64*t + lane);
      key = (g.w != 0.0f) ? key : ~0u;   // empty pad-groups excluded
      best = umin32(best, key);
    }
    const int own = row >> 4;
    if (lane == (own & 63)) best = (uint32_t)own;  // force own group (self in top-51)
    glist[wid][lane] = (unsigned short)(best & 0xFFFFu);
    // same-wave ds_write->ds_read: compiler inserts lgkmcnt wait

    // -- expansion, MLP-staged: 16 coalesced 256B group reads --
    int gidx[EXPK];
    #pragma unroll
    for (int k = 0; k < EXPK; ++k)
      gidx[k] = 16 * (int)glist[wid][4*k + (lane >> 4)] + (lane & 15);
    float4 cj_[EXPK];
    #pragma unroll
    for (int k = 0; k < EXPK; ++k) cj_[k] = scent[gidx[k]];

    uint32_t e0 = ~0u, e1 = ~0u, e2 = ~0u, e3 = ~0u;
    #pragma unroll
    for (int k = 0; k < EXPK; ++k) {
      if (gidx[k] < F) {
        float4 cj = cj_[k];
        float dot = fmaf(ci.x, cj.x, fmaf(ci.y, cj.y, ci.z * cj.z));
        float d2 = fmaxf(fmaf(-2.0f, dot, sqi + cj.w), 0.0f);
        uint32_t key = ((uint32_t)__half_as_ushort(__float2half_rn(d2)) << 16)
                       | (uint32_t)gidx[k];
        uint32_t c_ = key, t_;
        t_ = umin32(c_, e0); c_ = umax32(c_, e0); e0 = t_;
        t_ = umin32(c_, e1); c_ = umax32(c_, e1); e1 = t_;
        t_ = umin32(c_, e2); c_ = umax32(c_, e2); e2 = t_;
        e3 = umin32(c_, e3);
      }
    }

    // -- threshold: 51st smallest (self included, as top_k(51)) --
    uint32_t T2 = 0;
    #pragma unroll 1
    for (int bit = 14; bit >= 0; --bit) {
      uint32_t M = (T2 | (1u << bit)) << 16;
      int c = __popcll(__ballot(e0 < M)) + __popcll(__ballot(e1 < M)) +
              __popcll(__ballot(e2 < M)) + __popcll(__ballot(e3 < M));
      if (c < 51) T2 |= (1u << bit);
    }
    const uint32_t lim2 = (T2 + 1) << 16;

    // -- compact neighbor ids (exclude self), reuse glist row --
    const uint32_t rw = (uint32_t)row;
    bool q0 = e0 < lim2 && (e0 & 0xFFFFu) != rw;
    bool q1 = e1 < lim2 && (e1 & 0xFFFFu) != rw;
    bool q2 = e2 < lim2 && (e2 & 0xFFFFu) != rw;
    bool q3 = e3 < lim2 && (e3 & 0xFFFFu) != rw;
    unsigned long long f0 = __ballot(q0), f1 = __ballot(q1);
    unsigned long long f2 = __ballot(q2), f3 = __ballot(q3);
    int c0 = __popcll(f0);
    int c01 = c0 + __popcll(f1);
    int c012 = c01 + __popcll(f2);
    int n = c012 + __popcll(f3);
    int s0 = __popcll(f0 & below);
    int s1 = c0 + __popcll(f1 & below);
    int s2 = c01 + __popcll(f2 & below);
    int s3 = c012 + __popcll(f3 & below);
    if (q0 && s0 < 64) glist[wid][s0] = (unsigned short)(e0 & 0xFFFFu);
    if (q1 && s1 < 64) glist[wid][s1] = (unsigned short)(e1 & 0xFFFFu);
    if (q2 && s2 < 64) glist[wid][s2] = (unsigned short)(e2 & 0xFFFFu);
    if (q3 && s3 < 64) glist[wid][s3] = (unsigned short)(e3 & 0xFFFFu);

    // -- predicate --
    const float4 nui = snun[row];
    const float inv_i = 1.0f / (sqrtf(nui.x*nui.x + nui.y*nui.y + nui.z*nui.z) + 1e-8f);
    const float4 ai  = sqa[row];
    const float4 bi  = sqb[row];
    const float4 civ = sqc[row];
    const ushort4 fi = sfaces[row];
    const int fi0 = fi.x, fi1 = fi.y, fi2 = fi.z;
    const bool first1 = (fi1 != fi0);
    const bool first2 = (fi2 != fi0) && (fi2 != fi1);

    bool coll = false;
    if (lane < (n < 64 ? n : 64)) {
      int j = (int)glist[wid][lane];
      float4 nuj = snun[j];
      float inv_j = 1.0f / (sqrtf(nuj.x*nuj.x + nuj.y*nuj.y + nuj.z*nuj.z) + 1e-8f);
      float ndot = fabsf(nui.x*nuj.x + nui.y*nuj.y + nui.z*nuj.z) * inv_i * inv_j;
      float4 cj = scent[j];
      float dx = ci.x - cj.x, dy = ci.y - cj.y, dz = ci.z - cj.z;
      bool cop_hit = sqrtf(dx*dx + dy*dy + dz*dz) < 1e-10f;
      float4 aj = sqa[j], bj = sqb[j], cjv = sqc[j];
      float dA0 = (aj.x-ai.x)*nui.x + (aj.y-ai.y)*nui.y + (aj.z-ai.z)*nui.z;
      float dA1 = (bj.x-ai.x)*nui.x + (bj.y-ai.y)*nui.y + (bj.z-ai.z)*nui.z;
      float dA2 = (cjv.x-ai.x)*nui.x + (cjv.y-ai.y)*nui.y + (cjv.z-ai.z)*nui.z;
      bool condA = (dA0*dA1 <= 0.f) || (dA0*dA2 <= 0.f) || (dA1*dA2 <= 0.f);
      float dB0 = (ai.x-aj.x)*nuj.x + (ai.y-aj.y)*nuj.y + (ai.z-aj.z)*nuj.z;
      float dB1 = (bi.x-aj.x)*nuj.x + (bi.y-aj.y)*nuj.y + (bi.z-aj.z)*nuj.z;
      float dB2 = (civ.x-aj.x)*nuj.x + (civ.y-aj.y)*nuj.y + (civ.z-aj.z)*nuj.z;
      bool condB = (dB0*dB1 <= 0.f) || (dB0*dB2 <= 0.f) || (dB1*dB2 <= 0.f);
      bool inter = (ndot > 0.99f) ? cop_hit : (condA && condB);
      ushort4 gj = sfaces[j];
      int g0 = gj.x, g1 = gj.y, g2 = gj.z;
      int shared_ = 0;
      shared_ += ((fi0==g0) | (fi0==g1) | (fi0==g2)) ? 1 : 0;
      shared_ += (first1 && ((fi1==g0) | (fi1==g1) | (fi1==g2))) ? 1 : 0;
      shared_ += (first2 && ((fi2==g0) | (fi2==g1) | (fi2==g2))) ? 1 : 0;
      coll = inter && (shared_ < 2);
    }
    unsigned long long cm = __ballot(coll);
    if (lane == 0) atomicAdd(&blocksum, sprob[row] * (float)__popcll(cm));
  }

  __syncthreads();
  if (tid == 0) atomicAdd(out, blocksum);
}

extern "C" void kernel_launch(void* const* d_in, const int* in_sizes, int n_in,
                              void* d_out, int out_size, void* d_ws, size_t ws_size,
                              hipStream_t stream) {
  const float* verts = (const float*)d_in[0];
  const int*   faces = (const int*)d_in[1];
  const float* prob  = (const float*)d_in[2];
  float* out = (float*)d_out;
  int F = in_sizes[1] / 3;
  int Fpad = (F + 255) & ~255;        // 256-aligned; sortprep thread per slot
  Fpad = (Fpad + 2047) & ~2047;       // also 2048-aligned: 1280 groups of 16
  const int ngroups = Fpad / 16;      // 1280
  const int giters = ngroups / 64;    // 20
  const int pblocks = Fpad / 256;     // 80 (<= 256 CUs: co-resident)

  char* ws = (char*)d_ws;
  uint32_t* bar    = (uint32_t*)ws;                       ws += 32;
  uint32_t* hist   = (uint32_t*)ws;                       ws += NCELL * 4;
  float4* gcentsum = (float4*)ws;                         ws += (size_t)ngroups * 16;
  uint32_t* cursor = (uint32_t*)ws;                       ws += NCELL * 4;
  float4* scent = (float4*)ws;                            ws += (size_t)Fpad * 16;
  float4* snun  = (float4*)ws;                            ws += (size_t)Fpad * 16;
  float4* sqa   = (float4*)ws;                            ws += (size_t)Fpad * 16;
  float4* sqb   = (float4*)ws;                            ws += (size_t)Fpad * 16;
  float4* sqc   = (float4*)ws;                            ws += (size_t)Fpad * 16;
  ushort4* sfaces = (ushort4*)ws;                         ws += (size_t)Fpad * 8;
  float* sprob  = (float*)ws;                             ws += (size_t)Fpad * 4;

  // Node 1: zero bar + hist + gcentsum (contiguous prefix of ws).
  hipMemsetAsync(d_ws, 0, 32 + (size_t)NCELL * 4 + (size_t)ngroups * 16, stream);

  // Node 2: hist -> scan -> scatter (+group sums) in one multi-block kernel.
  sortprep_kernel<<<pblocks, 256, 0, stream>>>(
      verts, faces, prob, out, bar, hist, cursor,
      scent, snun, sqa, sqb, sqc, sfaces, sprob, gcentsum, F);

  // Node 3: kNN + collision.
  int blocks = (F + WPB - 1) / WPB;
  knn_collide_kernel<<<blocks, WPB * 64, 0, stream>>>(
      gcentsum, scent, snun, sqa, sqb, sqc, sfaces, sprob, out, F, giters);
}

// Round 13
// 131.049 us; speedup vs baseline: 4.8631x; 1.2830x over previous
//
#include <hip/hip_runtime.h>
#include <hip/hip_fp16.h>
#include <math.h>

#define WPB 4       // waves per block (knn); 2 rows per wave
#define EXPK 16     // expansion slots/lane = 64 groups * 16 / 64 lanes
#define NCELL 4096  // 16^3 Morton cells

__device__ __forceinline__ uint32_t umin32(uint32_t a, uint32_t b) { return a < b ? a : b; }
__device__ __forceinline__ uint32_t umax32(uint32_t a, uint32_t b) { return a > b ? a : b; }

__device__ __forceinline__ uint32_t expand5(uint32_t x) {
  x &= 0x1Fu;
  x = (x | (x << 8)) & 0x100Fu;
  x = (x | (x << 4)) & 0x10C3u;
  x = (x | (x << 2)) & 0x1249u;
  return x;
}
__device__ __forceinline__ uint32_t cell_of(float gx, float gy, float gz) {
  int cx = (int)((gx + 3.2f) * 2.5f);
  int cy = (int)((gy + 3.2f) * 2.5f);
  int cz = (int)((gz + 3.2f) * 2.5f);
  cx = cx < 0 ? 0 : (cx > 15 ? 15 : cx);
  cy = cy < 0 ? 0 : (cy > 15 ? 15 : cy);
  cz = cz < 0 ? 0 : (cz > 15 ? 15 : cz);
  return expand5((uint32_t)cx) | (expand5((uint32_t)cy) << 1) | (expand5((uint32_t)cz) << 2);
}

// ---- sortprep: hist(rank-returning) -> ONE arrive-all barrier ->
// per-block redundant scan (LDS cursor) -> scatter at base[cell]+rank.
// 80 blocks <= 256 CUs: co-resident by construction, spin cannot deadlock.
// bar/hist/gcentsum pre-zeroed by the hipMemsetAsync node.
__global__ __launch_bounds__(256) void sortprep_kernel(
    const float* __restrict__ verts, const int* __restrict__ faces,
    const float* __restrict__ prob, float* __restrict__ out,
    uint32_t* __restrict__ bar, uint32_t* __restrict__ hist,
    float4* __restrict__ scent, float4* __restrict__ snun,
    float4* __restrict__ sqa, float4* __restrict__ sqb, float4* __restrict__ sqc,
    ushort4* __restrict__ sfaces, float* __restrict__ sprob,
    float4* __restrict__ gcentsum, int F) {
  __shared__ uint32_t cbase[NCELL];
  __shared__ uint32_t wsums[4];
  const int tid = threadIdx.x;
  const int lane = tid & 63, wid = tid >> 6;
  const int f = blockIdx.x * 256 + tid;
  if (f == 0) out[0] = 0.0f;

  // -- phase A: centroid + cell; the hist atomic RETURNS the in-cell rank --
  bool valid = (f < F);
  int i0 = 0, i1 = 0, i2 = 0;
  float ax=0,ay=0,az=0,bx=0,by=0,bz=0,cx=0,cy=0,cz=0;
  float gx=0,gy=0,gz=0,sq=0;
  uint32_t cell = 0, rank = 0;
  if (valid) {
    i0 = faces[3*f+0]; i1 = faces[3*f+1]; i2 = faces[3*f+2];
    ax = verts[3*i0+0]; ay = verts[3*i0+1]; az = verts[3*i0+2];
    bx = verts[3*i1+0]; by = verts[3*i1+1]; bz = verts[3*i1+2];
    cx = verts[3*i2+0]; cy = verts[3*i2+1]; cz = verts[3*i2+2];
    gx = (ax+bx+cx)/3.0f; gy = (ay+by+cy)/3.0f; gz = (az+bz+cz)/3.0f;
    sq = gx*gx + gy*gy + gz*gz;
    cell = cell_of(gx, gy, gz);
    rank = atomicAdd(&hist[cell], 1u);
  }

  // -- ONE arrive-all barrier over 80 blocks --
  __syncthreads();
  if (tid == 0) {
    __threadfence();
    __hip_atomic_fetch_add(&bar[0], 1u, __ATOMIC_RELEASE, __HIP_MEMORY_SCOPE_AGENT);
    while (__hip_atomic_load(&bar[0], __ATOMIC_ACQUIRE, __HIP_MEMORY_SCOPE_AGENT)
           < gridDim.x)
      __builtin_amdgcn_s_sleep(2);
    __threadfence();
  }
  __syncthreads();

  // -- every block: redundant exclusive scan of final hist into LDS --
  uint32_t loc[16];
  uint32_t s = 0;
  const int base = tid * 16;   // 256 thr x 16 = 4096 cells
  #pragma unroll
  for (int i = 0; i < 16; ++i) { loc[i] = hist[base + i]; s += loc[i]; }
  uint32_t v = s;
  #pragma unroll
  for (int off = 1; off < 64; off <<= 1) {
    uint32_t u = (uint32_t)__shfl_up((int)v, off);
    if (lane >= off) v += u;
  }
  if (lane == 63) wsums[wid] = v;
  __syncthreads();
  if (wid == 0 && lane < 4) {
    uint32_t w = wsums[lane];
    #pragma unroll
    for (int off = 1; off < 4; off <<= 1) {
      uint32_t u = (uint32_t)__shfl_up((int)w, off);
      if (lane >= off) w += u;
    }
    wsums[lane] = w;
  }
  __syncthreads();
  uint32_t run = ((wid > 0) ? wsums[wid - 1] : 0u) + (v - s);
  #pragma unroll
  for (int i = 0; i < 16; ++i) { cbase[base + i] = run; run += loc[i]; }
  __syncthreads();

  // -- scatter into Morton-sorted order + group-sum atomics --
  if (valid) {
    float e1x = bx-ax, e1y = by-ay, e1z = bz-az;
    float e2x = cx-ax, e2y = cy-ay, e2z = cz-az;
    float nx = e1y*e2z - e1z*e2y;
    float ny = e1z*e2x - e1x*e2z;
    float nz = e1x*e2y - e1y*e2x;
    uint32_t pos = cbase[cell] + rank;
    scent[pos] = make_float4(gx, gy, gz, sq);
    snun[pos]  = make_float4(nx, ny, nz, 0.f);
    sqa[pos]   = make_float4(ax, ay, az, 0.f);
    sqb[pos]   = make_float4(bx, by, bz, 0.f);
    sqc[pos]   = make_float4(cx, cy, cz, 0.f);
    sfaces[pos] = make_ushort4((unsigned short)i0, (unsigned short)i1, (unsigned short)i2, 0u);
    sprob[pos] = prob[f];
    float* gs = (float*)&gcentsum[pos >> 4];
    atomicAdd(gs + 0, gx);
    atomicAdd(gs + 1, gy);
    atomicAdd(gs + 2, gz);
    atomicAdd(gs + 3, 1.0f);
  }
}

// ---- knn+collision: TWO rows per wave, fully interleaved (two independent
// latency chains overlap at the issue slot). Per-lane top-1 group over the
// lane's 20-group stripe; 64 groups -> 1024 candidates; exact f32 re-rank
// (f16-rounded keys); 51st-threshold; predicate.
__global__ __launch_bounds__(WPB * 64) void knn_collide_kernel(
    const float4* __restrict__ gcentsum,
    const float4* __restrict__ scent, const float4* __restrict__ snun,
    const float4* __restrict__ sqa, const float4* __restrict__ sqb,
    const float4* __restrict__ sqc, const ushort4* __restrict__ sfaces,
    const float* __restrict__ sprob,
    float* __restrict__ out, int F, int giters) {
  __shared__ float blocksum;
  __shared__ unsigned short listA[WPB][64];
  __shared__ unsigned short listB[WPB][64];
  const int tid = threadIdx.x;
  const int lane = tid & 63;
  const int wid = tid >> 6;
  const int rA = (blockIdx.x * WPB + wid) * 2;
  const int rB = rA + 1;
  if (tid == 0) blocksum = 0.f;
  __syncthreads();
  const bool vA = (rA < F), vB = (rB < F);
  const int cA = vA ? rA : 0, cB = vB ? rB : 0;
  const unsigned long long below = (lane == 0) ? 0ull : (~0ull >> (64 - lane));

  const float4 ciA = scent[cA];
  const float4 ciB = scent[cB];

  // -- scan: shared group load serves both rows; per-lane top-1 group --
  uint32_t bestA = ~0u, bestB = ~0u;
  for (int t = 0; t < giters; ++t) {
    float4 g = gcentsum[64*t + lane];
    float inv16 = 0.0625f;
    float mx = g.x * inv16, my = g.y * inv16, mz = g.z * inv16;
    float dxA = mx - ciA.x, dyA = my - ciA.y, dzA = mz - ciA.z;
    float dxB = mx - ciB.x, dyB = my - ciB.y, dzB = mz - ciB.z;
    float d2A = fmaf(dzA, dzA, fmaf(dyA, dyA, dxA*dxA));
    float d2B = fmaf(dzB, dzB, fmaf(dyB, dyB, dxB*dxB));
    uint32_t gi = (uint32_t)(64*t + lane);
    uint32_t kA = ((uint32_t)__half_as_ushort(__float2half_rn(d2A)) << 16) | gi;
    uint32_t kB = ((uint32_t)__half_as_ushort(__float2half_rn(d2B)) << 16) | gi;
    bool real = (g.w != 0.0f);
    bestA = umin32(bestA, real ? kA : ~0u);
    bestB = umin32(bestB, real ? kB : ~0u);
  }
  const int ownA = cA >> 4, ownB = cB >> 4;
  if (lane == (ownA & 63)) bestA = (uint32_t)ownA;  // own group (self in top-51)
  if (lane == (ownB & 63)) bestB = (uint32_t)ownB;

  // -- expansion: group ids via __shfl (no LDS), interleaved A/B --
  const float sqiA = ciA.w, sqiB = ciB.w;
  uint32_t eA0=~0u, eA1=~0u, eA2=~0u, eA3=~0u;
  uint32_t eB0=~0u, eB1=~0u, eB2=~0u, eB3=~0u;
  #pragma unroll
  for (int k = 0; k < EXPK; ++k) {
    int gslot = 4*k + (lane >> 4);
    int gidA = 16 * (__shfl((int)bestA, gslot) & 0xFFFF) + (lane & 15);
    int gidB = 16 * (__shfl((int)bestB, gslot) & 0xFFFF) + (lane & 15);
    float4 cjA = scent[gidA];
    float4 cjB = scent[gidB];
    {
      float dot = fmaf(ciA.x, cjA.x, fmaf(ciA.y, cjA.y, ciA.z * cjA.z));
      float d2 = fmaxf(fmaf(-2.0f, dot, sqiA + cjA.w), 0.0f);
      uint32_t key = ((uint32_t)__half_as_ushort(__float2half_rn(d2)) << 16)
                     | (uint32_t)gidA;
      if (gidA >= F) key = ~0u;
      uint32_t c_ = key, t_;
      t_ = umin32(c_, eA0); c_ = umax32(c_, eA0); eA0 = t_;
      t_ = umin32(c_, eA1); c_ = umax32(c_, eA1); eA1 = t_;
      t_ = umin32(c_, eA2); c_ = umax32(c_, eA2); eA2 = t_;
      eA3 = umin32(c_, eA3);
    }
    {
      float dot = fmaf(ciB.x, cjB.x, fmaf(ciB.y, cjB.y, ciB.z * cjB.z));
      float d2 = fmaxf(fmaf(-2.0f, dot, sqiB + cjB.w), 0.0f);
      uint32_t key = ((uint32_t)__half_as_ushort(__float2half_rn(d2)) << 16)
                     | (uint32_t)gidB;
      if (gidB >= F) key = ~0u;
      uint32_t c_ = key, t_;
      t_ = umin32(c_, eB0); c_ = umax32(c_, eB0); eB0 = t_;
      t_ = umin32(c_, eB1); c_ = umax32(c_, eB1); eB1 = t_;
      t_ = umin32(c_, eB2); c_ = umax32(c_, eB2); eB2 = t_;
      eB3 = umin32(c_, eB3);
    }
  }

  // -- threshold: 51st smallest, two independent chains interleaved --
  uint32_t TA = 0, TB = 0;
  #pragma unroll 1
  for (int bit = 14; bit >= 0; --bit) {
    uint32_t MA = (TA | (1u << bit)) << 16;
    uint32_t MB = (TB | (1u << bit)) << 16;
    int ca = __popcll(__ballot(eA0 < MA)) + __popcll(__ballot(eA1 < MA)) +
             __popcll(__ballot(eA2 < MA)) + __popcll(__ballot(eA3 < MA));
    int cb = __popcll(__ballot(eB0 < MB)) + __popcll(__ballot(eB1 < MB)) +
             __popcll(__ballot(eB2 < MB)) + __popcll(__ballot(eB3 < MB));
    if (ca < 51) TA |= (1u << bit);
    if (cb < 51) TB |= (1u << bit);
  }
  const uint32_t limA = (TA + 1) << 16;
  const uint32_t limB = (TB + 1) << 16;

  // -- compact neighbor ids (exclude self) into per-row LDS lists --
  int nA, nB;
  {
    const uint32_t rw = (uint32_t)rA;
    bool q0 = eA0 < limA && (eA0 & 0xFFFFu) != rw;
    bool q1 = eA1 < limA && (eA1 & 0xFFFFu) != rw;
    bool q2 = eA2 < limA && (eA2 & 0xFFFFu) != rw;
    bool q3 = eA3 < limA && (eA3 & 0xFFFFu) != rw;
    unsigned long long f0 = __ballot(q0), f1 = __ballot(q1);
    unsigned long long f2 = __ballot(q2), f3 = __ballot(q3);
    int c0 = __popcll(f0);
    int c01 = c0 + __popcll(f1);
    int c012 = c01 + __popcll(f2);
    nA = c012 + __popcll(f3);
    int s0 = __popcll(f0 & below);
    int s1 = c0 + __popcll(f1 & below);
    int s2 = c01 + __popcll(f2 & below);
    int s3 = c012 + __popcll(f3 & below);
    if (q0 && s0 < 64) listA[wid][s0] = (unsigned short)(eA0 & 0xFFFFu);
    if (q1 && s1 < 64) listA[wid][s1] = (unsigned short)(eA1 & 0xFFFFu);
    if (q2 && s2 < 64) listA[wid][s2] = (unsigned short)(eA2 & 0xFFFFu);
    if (q3 && s3 < 64) listA[wid][s3] = (unsigned short)(eA3 & 0xFFFFu);
  }
  {
    const uint32_t rw = (uint32_t)rB;
    bool q0 = eB0 < limB && (eB0 & 0xFFFFu) != rw;
    bool q1 = eB1 < limB && (eB1 & 0xFFFFu) != rw;
    bool q2 = eB2 < limB && (eB2 & 0xFFFFu) != rw;
    bool q3 = eB3 < limB && (eB3 & 0xFFFFu) != rw;
    unsigned long long f0 = __ballot(q0), f1 = __ballot(q1);
    unsigned long long f2 = __ballot(q2), f3 = __ballot(q3);
    int c0 = __popcll(f0);
    int c01 = c0 + __popcll(f1);
    int c012 = c01 + __popcll(f2);
    nB = c012 + __popcll(f3);
    int s0 = __popcll(f0 & below);
    int s1 = c0 + __popcll(f1 & below);
    int s2 = c01 + __popcll(f2 & below);
    int s3 = c012 + __popcll(f3 & below);
    if (q0 && s0 < 64) listB[wid][s0] = (unsigned short)(eB0 & 0xFFFFu);
    if (q1 && s1 < 64) listB[wid][s1] = (unsigned short)(eB1 & 0xFFFFu);
    if (q2 && s2 < 64) listB[wid][s2] = (unsigned short)(eB2 & 0xFFFFu);
    if (q3 && s3 < 64) listB[wid][s3] = (unsigned short)(eB3 & 0xFFFFu);
  }

  // -- predicate, interleaved A/B --
  float wsum = 0.f;
  const int jA = (lane < (nA < 64 ? nA : 64)) ? (int)listA[wid][lane] : cA;
  const int jB = (lane < (nB < 64 ? nB : 64)) ? (int)listB[wid][lane] : cB;
  bool actA = vA && (lane < (nA < 64 ? nA : 64));
  bool actB = vB && (lane < (nB < 64 ? nB : 64));

  const float4 nuiA = snun[cA], nuiB = snun[cB];
  const float4 aiA = sqa[cA],  aiB = sqa[cB];
  const float4 biA = sqb[cA],  biB = sqb[cB];
  const float4 civA = sqc[cA], civB = sqc[cB];
  const ushort4 fiA = sfaces[cA], fiB = sfaces[cB];
  const float4 nujA = snun[jA], nujB = snun[jB];
  const float4 cjA = scent[jA], cjB = scent[jB];
  const float4 ajA = sqa[jA],  ajB = sqa[jB];
  const float4 bjA = sqb[jA],  bjB = sqb[jB];
  const float4 cjvA = sqc[jA], cjvB = sqc[jB];
  const ushort4 gjA = sfaces[jA], gjB = sfaces[jB];

  bool collA, collB;
  {
    const float4 nui = nuiA, nuj = nujA, ci = ciA, cj = cjA;
    const float4 ai = aiA, bi = biA, civ = civA, aj = ajA, bj = bjA, cjv = cjvA;
    float inv_i = 1.0f / (sqrtf(nui.x*nui.x + nui.y*nui.y + nui.z*nui.z) + 1e-8f);
    float inv_j = 1.0f / (sqrtf(nuj.x*nuj.x + nuj.y*nuj.y + nuj.z*nuj.z) + 1e-8f);
    float ndot = fabsf(nui.x*nuj.x + nui.y*nuj.y + nui.z*nuj.z) * inv_i * inv_j;
    float dx = ci.x - cj.x, dy = ci.y - cj.y, dz = ci.z - cj.z;
    bool cop_hit = sqrtf(dx*dx + dy*dy + dz*dz) < 1e-10f;
    float dA0 = (aj.x-ai.x)*nui.x + (aj.y-ai.y)*nui.y + (aj.z-ai.z)*nui.z;
    float dA1 = (bj.x-ai.x)*nui.x + (bj.y-ai.y)*nui.y + (bj.z-ai.z)*nui.z;
    float dA2 = (cjv.x-ai.x)*nui.x + (cjv.y-ai.y)*nui.y + (cjv.z-ai.z)*nui.z;
    bool condA = (dA0*dA1 <= 0.f) || (dA0*dA2 <= 0.f) || (dA1*dA2 <= 0.f);
    float dB0 = (ai.x-aj.x)*nuj.x + (ai.y-aj.y)*nuj.y + (ai.z-aj.z)*nuj.z;
    float dB1 = (bi.x-aj.x)*nuj.x + (bi.y-aj.y)*nuj.y + (bi.z-aj.z)*nuj.z;
    float dB2 = (civ.x-aj.x)*nuj.x + (civ.y-aj.y)*nuj.y + (civ.z-aj.z)*nuj.z;
    bool condB = (dB0*dB1 <= 0.f) || (dB0*dB2 <= 0.f) || (dB1*dB2 <= 0.f);
    bool inter = (ndot > 0.99f) ? cop_hit : (condA && condB);
    int g0 = gjA.x, g1 = gjA.y, g2 = gjA.z;
    int fi0 = fiA.x, fi1 = fiA.y, fi2 = fiA.z;
    bool first1 = (fi1 != fi0), first2 = (fi2 != fi0) && (fi2 != fi1);
    int shared_ = 0;
    shared_ += ((fi0==g0) | (fi0==g1) | (fi0==g2)) ? 1 : 0;
    shared_ += (first1 && ((fi1==g0) | (fi1==g1) | (fi1==g2))) ? 1 : 0;
    shared_ += (first2 && ((fi2==g0) | (fi2==g1) | (fi2==g2))) ? 1 : 0;
    collA = actA && inter && (shared_ < 2);
  }
  {
    const float4 nui = nuiB, nuj = nujB, ci = ciB, cj = cjB;
    const float4 ai = aiB, bi = biB, civ = civB, aj = ajB, bj = bjB, cjv = cjvB;
    float inv_i = 1.0f / (sqrtf(nui.x*nui.x + nui.y*nui.y + nui.z*nui.z) + 1e-8f);
    float inv_j = 1.0f / (sqrtf(nuj.x*nuj.x + nuj.y*nuj.y + nuj.z*nuj.z) + 1e-8f);
    float ndot = fabsf(nui.x*nuj.x + nui.y*nuj.y + nui.z*nuj.z) * inv_i * inv_j;
    float dx = ci.x - cj.x, dy = ci.y - cj.y, dz = ci.z - cj.z;
    bool cop_hit = sqrtf(dx*dx + dy*dy + dz*dz) < 1e-10f;
    float dA0 = (aj.x-ai.x)*nui.x + (aj.y-ai.y)*nui.y + (aj.z-ai.z)*nui.z;
    float dA1 = (bj.x-ai.x)*nui.x + (bj.y-ai.y)*nui.y + (bj.z-ai.z)*nui.z;
    float dA2 = (cjv.x-ai.x)*nui.x + (cjv.y-ai.y)*nui.y + (cjv.z-ai.z)*nui.z;
    bool condA = (dA0*dA1 <= 0.f) || (dA0*dA2 <= 0.f) || (dA1*dA2 <= 0.f);
    float dB0 = (ai.x-aj.x)*nuj.x + (ai.y-aj.y)*nuj.y + (ai.z-aj.z)*nuj.z;
    float dB1 = (bi.x-aj.x)*nuj.x + (bi.y-aj.y)*nuj.y + (bi.z-aj.z)*nuj.z;
    float dB2 = (civ.x-aj.x)*nuj.x + (civ.y-aj.y)*nuj.y + (civ.z-aj.z)*nuj.z;
    bool condB = (dB0*dB1 <= 0.f) || (dB0*dB2 <= 0.f) || (dB1*dB2 <= 0.f);
    bool inter = (ndot > 0.99f) ? cop_hit : (condA && condB);
    int g0 = gjB.x, g1 = gjB.y, g2 = gjB.z;
    int fi0 = fiB.x, fi1 = fiB.y, fi2 = fiB.z;
    bool first1 = (fi1 != fi0), first2 = (fi2 != fi0) && (fi2 != fi1);
    int shared_ = 0;
    shared_ += ((fi0==g0) | (fi0==g1) | (fi0==g2)) ? 1 : 0;
    shared_ += (first1 && ((fi1==g0) | (fi1==g1) | (fi1==g2))) ? 1 : 0;
    shared_ += (first2 && ((fi2==g0) | (fi2==g1) | (fi2==g2))) ? 1 : 0;
    collB = actB && inter && (shared_ < 2);
  }
  unsigned long long cmA = __ballot(collA);
  unsigned long long cmB = __ballot(collB);
  if (lane == 0) {
    if (vA) wsum += sprob[rA] * (float)__popcll(cmA);
    if (vB) wsum += sprob[rB] * (float)__popcll(cmB);
    atomicAdd(&blocksum, wsum);
  }
  __syncthreads();
  if (tid == 0) atomicAdd(out, blocksum);
}

extern "C" void kernel_launch(void* const* d_in, const int* in_sizes, int n_in,
                              void* d_out, int out_size, void* d_ws, size_t ws_size,
                              hipStream_t stream) {
  const float* verts = (const float*)d_in[0];
  const int*   faces = (const int*)d_in[1];
  const float* prob  = (const float*)d_in[2];
  float* out = (float*)d_out;
  int F = in_sizes[1] / 3;
  int Fpad = (F + 2047) & ~2047;      // 20480: 1280 groups of 16
  const int ngroups = Fpad / 16;      // 1280
  const int giters = ngroups / 64;    // 20
  const int pblocks = Fpad / 256;     // 80 (<= 256 CUs: co-resident)

  char* ws = (char*)d_ws;
  uint32_t* bar    = (uint32_t*)ws;                       ws += 32;
  uint32_t* hist   = (uint32_t*)ws;                       ws += NCELL * 4;
  float4* gcentsum = (float4*)ws;                         ws += (size_t)ngroups * 16;
  float4* scent = (float4*)ws;                            ws += (size_t)Fpad * 16;
  float4* snun  = (float4*)ws;                            ws += (size_t)Fpad * 16;
  float4* sqa   = (float4*)ws;                            ws += (size_t)Fpad * 16;
  float4* sqb   = (float4*)ws;                            ws += (size_t)Fpad * 16;
  float4* sqc   = (float4*)ws;                            ws += (size_t)Fpad * 16;
  ushort4* sfaces = (ushort4*)ws;                         ws += (size_t)Fpad * 8;
  float* sprob  = (float*)ws;                             ws += (size_t)Fpad * 4;

  // Node 1: zero bar + hist + gcentsum (contiguous prefix of ws).
  hipMemsetAsync(d_ws, 0, 32 + (size_t)NCELL * 4 + (size_t)ngroups * 16, stream);

  // Node 2: hist(rank) -> barrier -> per-block scan -> scatter (+group sums).
  sortprep_kernel<<<pblocks, 256, 0, stream>>>(
      verts, faces, prob, out, bar, hist,
      scent, snun, sqa, sqb, sqc, sfaces, sprob, gcentsum, F);

  // Node 3: kNN + collision, 2 rows per wave.
  int rows_per_block = WPB * 2;
  int blocks = (F + rows_per_block - 1) / rows_per_block;
  knn_collide_kernel<<<blocks, WPB * 64, 0, stream>>>(
      gcentsum, scent, snun, sqa, sqb, sqc, sfaces, sprob, out, F, giters);
}